// Round 13
// baseline (4543.898 us; speedup 1.0000x reference)
//
#include <hip/hip_runtime.h>
#include <hip/hip_bf16.h>

// Problem constants
#define B_   64
#define T_   512
#define I_   512
#define H_   512
#define G_   5
#define NROW 2560   // G*H gate rows per direction
#define KD   512    // K depth
#define NBLK_REC 128

typedef __attribute__((ext_vector_type(8))) __bf16 bf16x8;
typedef __attribute__((ext_vector_type(4))) float  f32x4;
typedef __attribute__((ext_vector_type(2))) unsigned long long u64x2;
typedef unsigned long long u64;

#define MFMA16(A, Bf, C) __builtin_amdgcn_mfma_f32_16x16x32_bf16(A, Bf, C, 0, 0, 0)

__device__ __forceinline__ unsigned short f2bf(float f) {
  unsigned u = __builtin_bit_cast(unsigned, f);
  u = (u + 0x7fffu + ((u >> 16) & 1u)) >> 16;   // RNE
  return (unsigned short)u;
}
__device__ __forceinline__ float bf2f(unsigned short s) {
  unsigned u = ((unsigned)s) << 16;
  return __builtin_bit_cast(float, u);
}
__device__ __forceinline__ float sigm(float x) { return 1.f / (1.f + __expf(-x)); }
__device__ __forceinline__ float tanh_fast(float x) {
  return 1.f - 2.f / (__expf(2.f * x) + 1.f);
}
__device__ __forceinline__ u64 al64(const u64* p) {
  return __hip_atomic_load(p, __ATOMIC_RELAXED, __HIP_MEMORY_SCOPE_AGENT);
}
__device__ __forceinline__ unsigned al32(const unsigned* p) {
  return __hip_atomic_load(p, __ATOMIC_RELAXED, __HIP_MEMORY_SCOPE_AGENT);
}
__device__ __forceinline__ void st32(unsigned* p, unsigned v) {
  __hip_atomic_store(p, v, __ATOMIC_RELAXED, __HIP_MEMORY_SCOPE_AGENT);
}
__device__ __forceinline__ void pin_v(bf16x8& v) { asm volatile("" : "+v"(v)); }

// ---------------- ws layout (bytes) ----------------
#define OFF_XB   ((size_t)335544320)   // [B][T][I] bf16
#define OFF_W2X  ((size_t)369098752)
#define OFF_W2H  ((size_t)374341632)
#define OFF_BIAS ((size_t)379584512)
#define OFF_HB   ((size_t)379604992)
#define OFF_BAR  ((size_t)379867136)
#define WS_NEED  ((size_t)379871232)

// ---------------- sentinel (ws too small) ----------------
__global__ void k_sentinel(float* out, int n) {
  int i = blockIdx.x * 256 + threadIdx.x;
  if (i < n) out[i] = 10000.0f;
}

// ---------------- converts ----------------
__global__ void k_cvt_weights(const float* __restrict__ Wx_f, const float* __restrict__ Wh_f,
                              const float* __restrict__ Wx_b, const float* __restrict__ Wh_b,
                              const float* __restrict__ bx_f, const float* __restrict__ bh_f,
                              const float* __restrict__ bx_b, const float* __restrict__ bh_b,
                              unsigned short* __restrict__ W2x, unsigned short* __restrict__ W2h,
                              float* __restrict__ bias2) {
  int idx = blockIdx.x * 256 + threadIdx.x;       // exactly 2*NROW*KD threads
  int dir = idx / (NROW * KD);
  int r   = idx % (NROW * KD);
  W2x[idx] = f2bf(dir ? Wx_b[r] : Wx_f[r]);
  W2h[idx] = f2bf(dir ? Wh_b[r] : Wh_f[r]);
  if (idx < 2 * NROW) {
    int d2 = idx / NROW, n = idx % NROW;
    bias2[idx] = d2 ? (bx_b[n] + bh_b[n]) : (bx_f[n] + bh_f[n]);
  }
}

__global__ void k_cvt_x(const float* __restrict__ x, unsigned short* __restrict__ xb) {
  int idx = blockIdx.x * 256 + threadIdx.x;       // exactly B*T*I threads
  xb[idx] = f2bf(x[idx]);
}

__global__ void k_zero_h(unsigned short* __restrict__ hb, unsigned* __restrict__ bar) {
  int idx = blockIdx.x * 256 + threadIdx.x;       // exactly 2*2*B*H threads
  hb[idx] = 0;
  if (idx < 1024) bar[idx] = 0;
}

// ---------------- fused persistent kernel ----------------
// 128 blocks x 4 waves. Waves 0-1 dir f, waves 2-3 dir b (concurrent chains).
// Block bid owns units bid*4..bid*4+3 of each dir; wave handles 32 batches.
// Per step per wave:
//   poll -> h loads (agent u64) -> 64 rec-MFMA accumulating ON TOP of the
//   xp accumulator computed last step -> gate strip (wave-private LDS,
//   lgkmcnt only) -> cell update (+bias) -> h store -> vmcnt(0) -> flag ->
//   out store + xp-GEMM for the NEXT step (64 MFMA, x from L2-cached global,
//   Wx from LDS) filling the poll window with real work.
// xp never touches memory: same MFMA D-layout as the recurrent GEMM.
__global__ __launch_bounds__(256, 1) void k_recurrent(
    const unsigned short* __restrict__ W2h,  // [2][NROW][KD]
    const unsigned short* __restrict__ W2x,  // [2][NROW][KD]
    const unsigned short* __restrict__ xb,   // [B][T][I] bf16
    const float* __restrict__ bias2,         // [2][NROW]  (bx+bh)
    unsigned short* __restrict__ hbuf,       // [buf][dir][128c][64b][4u]
    float* __restrict__ out,                 // [B][T][2H]
    unsigned* __restrict__ bar)              // [2][256] wave-flags
{
  const int tid = threadIdx.x;
  const int lane = tid & 63, wv = tid >> 6;
  const int bid = blockIdx.x;
  const int dirw = wv >> 1;                  // 0 = f, 1 = b
  const int mh   = wv & 1;                   // batch half
  const int l15 = lane & 15, l4 = lane >> 4;

  __shared__ unsigned short wx_sh[2][20 * 520];   // Wx rows, both dirs (41.6KB)
  __shared__ float g_sh[4][32 * 21];              // per-wave gate strips

  // ---- stage Wx (this block's 4 units x 5 gates, both dirs) into LDS ----
  // 2 dirs x 20 rows x 64 segs(16B) = 2560 segs
#pragma unroll
  for (int it = 0; it < 10; ++it) {
    int seg = it * 256 + tid;
    int d = seg / 1280, rs = seg % 1280;
    int r = rs >> 6, c8 = rs & 63;
    int g = r >> 2, ul = r & 3;
    const unsigned short* src =
        W2x + ((size_t)d * NROW + g * H_ + bid * 4 + ul) * KD + c8 * 8;
    *(bf16x8*)(&wx_sh[d][r * 520 + c8 * 8]) = *(const bf16x8*)src;
  }
  __syncthreads();

  float* gl = g_sh[wv];

  // ---- load + pin 32 Wh fragments (2 N-tiles x 16 ks), once ----
  bf16x8 wf0[16], wf1[16];
  {
    const unsigned short* w0 =
        W2h + ((size_t)dirw * NROW + (l15 >> 2) * H_ + bid * 4 + (l15 & 3)) * KD;
    int r1w = 16 + l15; if (r1w >= 20) r1w = 0;
    const unsigned short* w1 =
        W2h + ((size_t)dirw * NROW + (r1w >> 2) * H_ + bid * 4 + (r1w & 3)) * KD;
#pragma unroll
    for (int ks = 0; ks < 16; ++ks) {
      wf0[ks] = *(const bf16x8*)(w0 + ks * 32 + l4 * 8);
      wf1[ks] = *(const bf16x8*)(w1 + ks * 32 + l4 * 8);
      pin_v(wf0[ks]); pin_v(wf1[ks]);
    }
  }

  // Wx fragment base pointers in LDS (same N-tile mapping as wf0/wf1)
  const unsigned short* wx0 = &wx_sh[dirw][l15 * 520 + l4 * 8];
  int r1x = 16 + l15; if (r1x >= 20) r1x = 0;
  const unsigned short* wx1 = &wx_sh[dirw][r1x * 520 + l4 * 8];

  const unsigned short* hc = hbuf + (size_t)dirw * B_ * H_;        // buf 0
  unsigned short*       hn = hbuf + (size_t)(2 + dirw) * B_ * H_;  // buf 1
  unsigned* fl = bar + dirw * 256;
  const int myflag = bid * 2 + mh;

  const int bl  = lane >> 1;
  const int bg  = mh * 32 + bl;              // global batch of my cells
  const int up2 = (lane & 1) * 2;            // local unit pair (0 or 2)
  float kst0 = 0.f, kp0 = 0.f, kst1 = 0.f, kp1 = 0.f;

  // per-thread gate biases for my 2 cells (bx+bh, fp32)
  float bp[5], bq[5];
#pragma unroll
  for (int g = 0; g < 5; ++g) {
    bp[g] = bias2[dirw * NROW + g * H_ + bid * 4 + up2];
    bq[g] = bias2[dirw * NROW + g * H_ + bid * 4 + up2 + 1];
  }

  f32x4 zz4 = {0.f, 0.f, 0.f, 0.f};
  f32x4 xa00, xa01, xa10, xa11;              // xp accumulator for next step

  // xp-GEMM for step sp: A = x[batch][trow][k], B = Wx (LDS). 64 MFMA.
  auto compute_xp = [&](int sp) {
    int trow = dirw ? (T_ - 1 - sp) : sp;
    const unsigned short* xA0 =
        xb + ((size_t)(mh * 32 + l15) * T_ + trow) * I_ + l4 * 8;
    const unsigned short* xA1 =
        xb + ((size_t)(mh * 32 + 16 + l15) * T_ + trow) * I_ + l4 * 8;
    f32x4 a00 = zz4, a01 = zz4, a10 = zz4, a11 = zz4;
#pragma unroll
    for (int ks = 0; ks < 16; ++ks) {
      bf16x8 a0 = *(const bf16x8*)(xA0 + ks * 32);
      bf16x8 a1 = *(const bf16x8*)(xA1 + ks * 32);
      bf16x8 b0 = *(const bf16x8*)(wx0 + ks * 32);
      bf16x8 b1 = *(const bf16x8*)(wx1 + ks * 32);
      a00 = MFMA16(a0, b0, a00);
      a01 = MFMA16(a0, b1, a01);
      a10 = MFMA16(a1, b0, a10);
      a11 = MFMA16(a1, b1, a11);
    }
    xa00 = a00; xa01 = a01; xa10 = a10; xa11 = a11;
  };
  compute_xp(0);                             // prologue: xp for step 0

  for (int s = 0; s < T_; ++s) {
    if (s) {
      __builtin_amdgcn_sched_barrier(0);
      unsigned tgt = (unsigned)s;
      for (;;) {
        unsigned a = al32(fl + lane);
        unsigned b = al32(fl + 64 + lane);
        unsigned c = al32(fl + 128 + lane);
        unsigned d = al32(fl + 192 + lane);
        unsigned m0 = a < b ? a : b, m1 = c < d ? c : d;
        unsigned v = m0 < m1 ? m0 : m1;
        if (!__any(v < tgt)) break;
        __builtin_amdgcn_s_sleep(1);
      }
      __builtin_amdgcn_sched_barrier(0);
    }

    // recurrent GEMM: init from xp accumulator, add Wh·h
    const u64* hq = (const u64*)hc;
    f32x4 acc00 = xa00, acc01 = xa01, acc10 = xa10, acc11 = xa11;
    // M-tile 0 (batches mh*32 .. +15)
    {
      int batch = mh * 32 + l15;
      u64 lo[16], hi[16];
#pragma unroll
      for (int ks = 0; ks < 16; ++ks) {
        int c = ks * 8 + l4 * 2;
        lo[ks] = al64(hq + c * 64 + batch);
        hi[ks] = al64(hq + (c + 1) * 64 + batch);
      }
#pragma unroll
      for (int ks = 0; ks < 16; ++ks) {
        u64x2 t2 = {lo[ks], hi[ks]};
        bf16x8 a = __builtin_bit_cast(bf16x8, t2);
        acc00 = MFMA16(a, wf0[ks], acc00);
        acc01 = MFMA16(a, wf1[ks], acc01);
      }
    }
    // M-tile 1 (batches mh*32+16 .. +31)
    {
      int batch = mh * 32 + 16 + l15;
      u64 lo[16], hi[16];
#pragma unroll
      for (int ks = 0; ks < 16; ++ks) {
        int c = ks * 8 + l4 * 2;
        lo[ks] = al64(hq + c * 64 + batch);
        hi[ks] = al64(hq + (c + 1) * 64 + batch);
      }
#pragma unroll
      for (int ks = 0; ks < 16; ++ks) {
        u64x2 t2 = {lo[ks], hi[ks]};
        bf16x8 a = __builtin_bit_cast(bf16x8, t2);
        acc10 = MFMA16(a, wf0[ks], acc10);
        acc11 = MFMA16(a, wf1[ks], acc11);
      }
    }

    // dump D to this wave's private strip
#pragma unroll
    for (int rr = 0; rr < 4; ++rr) {
      int b0 = l4 * 4 + rr;
      gl[b0 * 21 + l15] = acc00[rr];
      if (l15 < 4) gl[b0 * 21 + 16 + l15] = acc01[rr];
      int b1 = 16 + l4 * 4 + rr;
      gl[b1 * 21 + l15] = acc10[rr];
      if (l15 < 4) gl[b1 * 21 + 16 + l15] = acc11[rr];
    }
    asm volatile("s_waitcnt lgkmcnt(0)" ::: "memory");
    __builtin_amdgcn_sched_barrier(0);

    // cell update for my 2 cells (+bias; xp already inside the gates)
    float p[5], q[5];
#pragma unroll
    for (int g = 0; g < 5; ++g) {
      p[g] = gl[bl * 21 + g * 4 + up2]     + bp[g];
      q[g] = gl[bl * 21 + g * 4 + up2 + 1] + bq[g];
    }
    float f0 = sigm(p[0]), i0 = sigm(p[1]), o0 = sigm(p[2]), u0 = sigm(p[3]), t0 = tanh_fast(p[4]);
    kp0  = u0 * t0 + (1.f - u0) * kp0;
    kst0 = f0 * kst0 + i0 * kp0;
    float hv0 = o0 * tanh_fast(kst0);
    float f1 = sigm(q[0]), i1 = sigm(q[1]), o1 = sigm(q[2]), u1 = sigm(q[3]), t1 = tanh_fast(q[4]);
    kp1  = u1 * t1 + (1.f - u1) * kp1;
    kst1 = f1 * kst1 + i1 * kp1;
    float hv1 = o1 * tanh_fast(kst1);

    // publish h (agent store), coalesced 256B per wave
    unsigned hw = (unsigned)f2bf(hv0) | ((unsigned)f2bf(hv1) << 16);
    st32((unsigned*)hn + bid * 128 + bg * 2 + (lane & 1), hw);

    int tout = dirw ? (T_ - 1 - s) : s;
    float2 ov = {hv0, hv1};
    if (s + 1 < T_) {
      asm volatile("s_waitcnt vmcnt(0)" ::: "memory");   // h store acked
      st32(&fl[myflag], (unsigned)(s + 1));              // own wave-flag
      // fill the poll window with real work:
      *(float2*)&out[((size_t)bg * T_ + tout) * (2 * H_) + dirw * H_ + bid * 4 + up2] = ov;
      compute_xp(s + 1);                                 // 64 MFMA + x loads
    } else {
      *(float2*)&out[((size_t)bg * T_ + tout) * (2 * H_) + dirw * H_ + bid * 4 + up2] = ov;
    }

    const unsigned short* tp = hc; hc = hn; hn = (unsigned short*)tp;
  }
}

// ---------------- launch ----------------
extern "C" void kernel_launch(void* const* d_in, const int* in_sizes, int n_in,
                              void* d_out, int out_size, void* d_ws, size_t ws_size,
                              hipStream_t stream) {
  const float* x    = (const float*)d_in[0];
  const float* Wx_f = (const float*)d_in[1];
  const float* bx_f = (const float*)d_in[2];
  const float* Wh_f = (const float*)d_in[3];
  const float* bh_f = (const float*)d_in[4];
  const float* Wx_b = (const float*)d_in[5];
  const float* bx_b = (const float*)d_in[6];
  const float* Wh_b = (const float*)d_in[7];
  const float* bh_b = (const float*)d_in[8];
  float* out = (float*)d_out;

  if (ws_size < WS_NEED) {
    k_sentinel<<<(out_size + 255) / 256, 256, 0, stream>>>(out, out_size);
    return;
  }

  char* ws = (char*)d_ws;
  unsigned short* xb    = (unsigned short*)(ws + OFF_XB);
  unsigned short* W2x   = (unsigned short*)(ws + OFF_W2X);
  unsigned short* W2h   = (unsigned short*)(ws + OFF_W2H);
  float*          bias2 = (float*)(ws + OFF_BIAS);
  unsigned short* hbuf  = (unsigned short*)(ws + OFF_HB);
  unsigned*       bar   = (unsigned*)(ws + OFF_BAR);

  k_cvt_weights<<<(2 * NROW * KD) / 256, 256, 0, stream>>>(
      Wx_f, Wh_f, Wx_b, Wh_b, bx_f, bh_f, bx_b, bh_b, W2x, W2h, bias2);
  k_cvt_x<<<(B_ * T_ * I_) / 256, 256, 0, stream>>>(x, xb);
  k_zero_h<<<512, 256, 0, stream>>>(hbuf, bar);
  k_recurrent<<<NBLK_REC, 256, 0, stream>>>(W2h, W2x, xb, bias2, hbuf, out, bar);
}

// Round 14
// 2552.936 us; speedup vs baseline: 1.7799x; 1.7799x over previous
//
#include <hip/hip_runtime.h>
#include <hip/hip_bf16.h>

// Problem constants
#define B_   64
#define T_   512
#define I_   512
#define H_   512
#define G_   5
#define NROW 2560   // G*H gate rows per direction
#define KD   512    // K depth

typedef __attribute__((ext_vector_type(8))) __bf16 bf16x8;
typedef __attribute__((ext_vector_type(4))) float  f32x4;
typedef __attribute__((ext_vector_type(2))) unsigned long long u64x2;
typedef unsigned long long u64;

#define MFMA16(A, Bf, C) __builtin_amdgcn_mfma_f32_16x16x32_bf16(A, Bf, C, 0, 0, 0)

__device__ __forceinline__ unsigned short f2bf(float f) {
  unsigned u = __builtin_bit_cast(unsigned, f);
  u = (u + 0x7fffu + ((u >> 16) & 1u)) >> 16;   // RNE
  return (unsigned short)u;
}
__device__ __forceinline__ float bf2f(unsigned short s) {
  unsigned u = ((unsigned)s) << 16;
  return __builtin_bit_cast(float, u);
}
__device__ __forceinline__ float sigm(float x) { return 1.f / (1.f + __expf(-x)); }
__device__ __forceinline__ float tanh_fast(float x) {
  return 1.f - 2.f / (__expf(2.f * x) + 1.f);
}
__device__ __forceinline__ u64 al64(const u64* p) {
  return __hip_atomic_load(p, __ATOMIC_RELAXED, __HIP_MEMORY_SCOPE_AGENT);
}
__device__ __forceinline__ void as64(u64* p, u64 v) {
  __hip_atomic_store(p, v, __ATOMIC_RELAXED, __HIP_MEMORY_SCOPE_AGENT);
}
__device__ __forceinline__ unsigned al32(const unsigned* p) {
  return __hip_atomic_load(p, __ATOMIC_RELAXED, __HIP_MEMORY_SCOPE_AGENT);
}
__device__ __forceinline__ void st32(unsigned* p, unsigned v) {
  __hip_atomic_store(p, v, __ATOMIC_RELAXED, __HIP_MEMORY_SCOPE_AGENT);
}

// ---------------- ws layout (bytes) ----------------
#define OFF_XP   ((size_t)0)
#define OFF_XB   ((size_t)335544320)
#define OFF_W2X  ((size_t)369098752)
#define OFF_W2H  ((size_t)374341632)
#define OFF_BIAS ((size_t)379584512)
#define OFF_HB   ((size_t)379604992)
#define OFF_BAR  ((size_t)379867136)
#define WS_NEED  ((size_t)379871232)

// ---------------- sentinel (ws too small) ----------------
__global__ void k_sentinel(float* out, int n) {
  int i = blockIdx.x * 256 + threadIdx.x;
  if (i < n) out[i] = 10000.0f;
}

// ---------------- converts ----------------
__global__ void k_cvt_weights(const float* __restrict__ Wx_f, const float* __restrict__ Wh_f,
                              const float* __restrict__ Wx_b, const float* __restrict__ Wh_b,
                              const float* __restrict__ bx_f, const float* __restrict__ bh_f,
                              const float* __restrict__ bx_b, const float* __restrict__ bh_b,
                              unsigned short* __restrict__ W2x, unsigned short* __restrict__ W2h,
                              float* __restrict__ bias2) {
  int idx = blockIdx.x * 256 + threadIdx.x;       // exactly 2*NROW*KD threads
  int dir = idx / (NROW * KD);
  int r   = idx % (NROW * KD);
  W2x[idx] = f2bf(dir ? Wx_b[r] : Wx_f[r]);
  W2h[idx] = f2bf(dir ? Wh_b[r] : Wh_f[r]);
  if (idx < 2 * NROW) {
    int d2 = idx / NROW, n = idx % NROW;
    bias2[idx] = d2 ? (bx_b[n] + bh_b[n]) : (bx_f[n] + bh_f[n]);
  }
}

__global__ void k_cvt_x(const float* __restrict__ x, unsigned short* __restrict__ xb) {
  int idx = blockIdx.x * 256 + threadIdx.x;       // exactly B*T*I threads
  xb[idx] = f2bf(x[idx]);
}

__global__ void k_zero_h(unsigned short* __restrict__ hb, unsigned* __restrict__ bar) {
  int idx = blockIdx.x * 256 + threadIdx.x;       // exactly 2*2*B*H threads
  hb[idx] = 0;
  if (idx < 1024) bar[idx] = 0;
}

// ---------------- phase 1: xp = Wx · x^T (+bias), both dirs ----------------
__global__ __launch_bounds__(256) void k_gemm_xp(
    const unsigned short* __restrict__ W2x,   // [2][NROW][KD]
    const unsigned short* __restrict__ xb,    // [B][T][I]
    const float* __restrict__ bias2,          // [2][NROW]
    unsigned short* __restrict__ xp)          // [2][T][NROW][B]
{
  const int tid = threadIdx.x;
  const int lane = tid & 63, wv = tid >> 6;
  int bz = blockIdx.x;
  const int dir = bz / (20 * 256); bz %= (20 * 256);
  const int nblk = bz / 256, mblk = bz % 256;
  const int n0 = nblk * 128, m0 = mblk * 128;
  const int l15 = lane & 15, l4 = lane >> 4;
  const int nh = wv >> 1, mh = wv & 1;

  __shared__ unsigned short Al[128 * 72];
  __shared__ unsigned short Bl[128 * 72];

  const unsigned short* Wd = W2x + (size_t)dir * NROW * KD;

  f32x4 acc[4][4];
  f32x4 zz = {0.f, 0.f, 0.f, 0.f};
#pragma unroll
  for (int i = 0; i < 4; ++i)
#pragma unroll
    for (int j = 0; j < 4; ++j) acc[i][j] = zz;

  for (int k0 = 0; k0 < KD; k0 += 64) {
#pragma unroll
    for (int j = 0; j < 4; ++j) {
      int sg = j * 256 + tid;
      int row = sg >> 3, ko = (sg & 7) * 8;
      bf16x8 va = *(const bf16x8*)(Wd + (size_t)(n0 + row) * KD + k0 + ko);
      *(bf16x8*)(Al + row * 72 + ko) = va;
      int m = m0 + row;
      int ss = m >> 6, b = m & 63;
      int trow = dir ? (T_ - 1 - ss) : ss;
      bf16x8 vb = *(const bf16x8*)(xb + ((size_t)b * T_ + trow) * I_ + k0 + ko);
      *(bf16x8*)(Bl + row * 72 + ko) = vb;
    }
    __syncthreads();
#pragma unroll
    for (int kk = 0; kk < 2; ++kk) {
      bf16x8 af[4], bfr[4];
#pragma unroll
      for (int f = 0; f < 4; ++f) {
        af[f]  = *(const bf16x8*)(Al + (nh * 64 + f * 16 + l15) * 72 + kk * 32 + l4 * 8);
        bfr[f] = *(const bf16x8*)(Bl + (mh * 64 + f * 16 + l15) * 72 + kk * 32 + l4 * 8);
      }
#pragma unroll
      for (int fi = 0; fi < 4; ++fi)
#pragma unroll
        for (int fj = 0; fj < 4; ++fj)
          acc[fi][fj] = MFMA16(af[fi], bfr[fj], acc[fi][fj]);
    }
    __syncthreads();
  }

#pragma unroll
  for (int fi = 0; fi < 4; ++fi) {
#pragma unroll
    for (int fj = 0; fj < 4; ++fj) {
#pragma unroll
      for (int r = 0; r < 4; ++r) {
        int n = n0 + nh * 64 + fi * 16 + l4 * 4 + r;
        int m = m0 + mh * 64 + fj * 16 + l15;
        int ss = m >> 6, b = m & 63;
        float v = acc[fi][fj][r] + bias2[dir * NROW + n];
        xp[(((size_t)dir * T_ + ss) * NROW + n) * 64 + b] = f2bf(v);
      }
    }
  }
}

// ---------------- phase 2: batch-half split persistent kernel ----------------
// 128 blocks x 128 threads (2 waves). bid: dir=bid&1, bhalf=(bid>>1)&1,
// ublk=bid>>2 (16 units). Wave w = M-tile w: 16 batches x 80 gate rows,
// 80 MFMA/step, reads h[16 b][512] = 16KB (half the old all-gather).
// Dependence factorizes into 8 independent 32-wave rendezvous
// (dir x bhalf x mtile): wave polls only its 32 producer flags.
// Weights in LDS (80x520), 2-deep N-tile double buffer pipelined under MFMA.
// No intra-block sync in the step loop; per-wave private gate/xp strips.
#define GSTEP(CUR, NXT, NT, NP)                                            \
  {                                                                        \
    _Pragma("unroll")                                                      \
    for (int ks = 0; ks < 16; ++ks)                                        \
      NXT[ks] = *(const bf16x8*)(w_lds + ((NP)*16 + l15) * 520 + ks * 32 + l4 * 8); \
    _Pragma("unroll")                                                      \
    for (int ks = 0; ks < 16; ++ks) {                                      \
      u64x2 t2 = {lo[ks], hi[ks]};                                         \
      bf16x8 a = __builtin_bit_cast(bf16x8, t2);                           \
      acc[NT] = MFMA16(a, CUR[ks], acc[NT]);                               \
    }                                                                      \
  }

__global__ __launch_bounds__(128, 1) void k_recurrent(
    const unsigned short* __restrict__ W2h,  // [2][NROW][KD]
    const unsigned short* __restrict__ xp,   // [2][T][NROW][B]
    unsigned short* __restrict__ hbuf,       // [buf][dir][64 b][512 u]
    float* __restrict__ out,                 // [B][T][2H]
    unsigned* __restrict__ bar)              // [2dir x 2half][64] wave-flags
{
  const int tid = threadIdx.x;
  const int lane = tid & 63, w = tid >> 6;     // w = M-tile (0/1)
  const int bid = blockIdx.x;
  const int dir = bid & 1, bhalf = (bid >> 1) & 1, ublk = bid >> 2;  // ublk<32
  const int l15 = lane & 15, l4 = lane >> 4;

  __shared__ unsigned short w_lds[80 * 520];   // 83.2 KB
  __shared__ float          g_sh[2][16 * 84];  // 10.8 KB (per-wave strips)
  __shared__ unsigned short x_sh[2][80 * 18];  //  5.8 KB

  // ---- stage Wh (80 rows x 512) into LDS: 5120 segs of 16B / 128 thr ----
  for (int it = 0; it < 40; ++it) {
    int seg = it * 128 + tid;
    int r = seg >> 6, c8 = seg & 63;           // row r: gate r>>4, unit r&15
    const unsigned short* src =
        W2h + ((size_t)dir * NROW + (r >> 4) * H_ + ublk * 16 + (r & 15)) * KD + c8 * 8;
    *(bf16x8*)(w_lds + r * 520 + c8 * 8) = *(const bf16x8*)src;
  }
  __syncthreads();

  float* gl = g_sh[w];
  unsigned short* xl = x_sh[w];

  const unsigned short* xpd = xp + (size_t)dir * T_ * NROW * 64;
  const int xoff = bhalf * 16 + w * 8;         // u32 offset within xp row
  const int batch0 = bhalf * 32 + w * 16;      // wave's global batch base

  unsigned* fl = bar + (dir * 2 + bhalf) * 64;
  const int myflag = ublk * 2 + w;

  const unsigned short* hc = hbuf + (size_t)dir * B_ * H_;        // buf 0
  unsigned short*       hn = hbuf + (size_t)(2 + dir) * B_ * H_;  // buf 1

  // cells: lane -> batch bl = lane>>2 (0..15), unit quad uq = (lane&3)*4
  const int bl = lane >> 2, uq = (lane & 3) * 4;
  float kst[4] = {0.f, 0.f, 0.f, 0.f}, kp[4] = {0.f, 0.f, 0.f, 0.f};

  // xp regs (10 u32 per wave-step)
  unsigned xr[10];
  auto ld_xp = [&](int s) {
    const unsigned* xb32 = (const unsigned*)(xpd + (size_t)s * NROW * 64);
#pragma unroll
    for (int j = 0; j < 10; ++j) {
      int id = j * 64 + lane;
      int r = id >> 3, c = id & 7;
      xr[j] = xb32[((size_t)(r >> 4) * H_ + ublk * 16 + (r & 15)) * 32 + xoff + c];
    }
  };
  ld_xp(0);

  f32x4 zz = {0.f, 0.f, 0.f, 0.f};
  bf16x8 wfA[16], wfB[16];
#pragma unroll
  for (int ks = 0; ks < 16; ++ks)              // preload N-tile 0
    wfA[ks] = *(const bf16x8*)(w_lds + l15 * 520 + ks * 32 + l4 * 8);

  auto body = [&](int s, bf16x8 (&cw)[16], bf16x8 (&nw)[16]) {
    if (s) {
      __builtin_amdgcn_sched_barrier(0);
      unsigned tgt = (unsigned)s;
      for (;;) {
        // dependency-exact poll: only the 32 producers of my (bhalf, mtile)
        unsigned v = al32(fl + (lane & 31) * 2 + w);
        if (!__any(v < tgt)) break;
        __builtin_amdgcn_s_sleep(1);
      }
      __builtin_amdgcn_sched_barrier(0);
    }

    // commit xp (loaded pre-poll) into this wave's strip
#pragma unroll
    for (int j = 0; j < 10; ++j) {
      int id = j * 64 + lane;
      int r = id >> 3, c = id & 7;
      *(unsigned*)(xl + r * 18 + c * 2) = xr[j];
    }

    // h loads: 16 batches x 512 units (agent u64, 16KB/wave)
    const u64* hq = (const u64*)hc;
    u64 lo[16], hi[16];
#pragma unroll
    for (int ks = 0; ks < 16; ++ks) {
      size_t ci = (size_t)(batch0 + l15) * 128 + ks * 8 + l4 * 2;
      lo[ks] = al64(hq + ci);
      hi[ks] = al64(hq + ci + 1);
    }

    // 80 MFMA: 5 N-tiles, weight frags double-buffered from LDS.
    // Last stage prefetches N-tile 0 for the NEXT step into nw.
    f32x4 acc[5] = {zz, zz, zz, zz, zz};
    GSTEP(cw, nw, 0, 1)
    GSTEP(nw, cw, 1, 2)
    GSTEP(cw, nw, 2, 3)
    GSTEP(nw, cw, 3, 4)
    GSTEP(cw, nw, 4, 0)

    // dump gates to per-wave strip: row = batch (l4*4+rr), col = gate row
#pragma unroll
    for (int Nt = 0; Nt < 5; ++Nt)
#pragma unroll
      for (int rr = 0; rr < 4; ++rr)
        gl[(l4 * 4 + rr) * 84 + Nt * 16 + l15] = acc[Nt][rr];
    asm volatile("s_waitcnt lgkmcnt(0)" ::: "memory");
    __builtin_amdgcn_sched_barrier(0);

    // cell update: 4 cells (batch bl, units uq..uq+3)
    float hv[4];
#pragma unroll
    for (int j = 0; j < 4; ++j) {
      int u = uq + j;
      float g0 = gl[bl * 84 + 0 * 16 + u] + bf2f(xl[(0 * 16 + u) * 18 + bl]);
      float g1 = gl[bl * 84 + 1 * 16 + u] + bf2f(xl[(1 * 16 + u) * 18 + bl]);
      float g2 = gl[bl * 84 + 2 * 16 + u] + bf2f(xl[(2 * 16 + u) * 18 + bl]);
      float g3 = gl[bl * 84 + 3 * 16 + u] + bf2f(xl[(3 * 16 + u) * 18 + bl]);
      float g4 = gl[bl * 84 + 4 * 16 + u] + bf2f(xl[(4 * 16 + u) * 18 + bl]);
      float ff = sigm(g0), ii = sigm(g1), oo = sigm(g2), uu = sigm(g3), tk = tanh_fast(g4);
      kp[j]  = uu * tk + (1.f - uu) * kp[j];
      kst[j] = ff * kst[j] + ii * kp[j];
      hv[j]  = oo * tanh_fast(kst[j]);
    }

    // publish h: 4 bf16 = one u64, coalesced 32B runs per batch
    u64 hw = (u64)f2bf(hv[0]) | ((u64)f2bf(hv[1]) << 16) |
             ((u64)f2bf(hv[2]) << 32) | ((u64)f2bf(hv[3]) << 48);
    as64((u64*)hn + (size_t)(batch0 + bl) * 128 + (ublk * 16 + uq) / 4, hw);

    int tout = dir ? (T_ - 1 - s) : s;
    float4 o4 = {hv[0], hv[1], hv[2], hv[3]};
    if (s + 1 < T_) {
      asm volatile("s_waitcnt vmcnt(0)" ::: "memory");   // h store acked
      st32(&fl[myflag], (unsigned)(s + 1));              // own wave-flag
      // off-critical-path: out store + next xp load overlap the poll
      *(float4*)&out[((size_t)(batch0 + bl) * T_ + tout) * (2 * H_) +
                     dir * H_ + ublk * 16 + uq] = o4;
      ld_xp(s + 1);
    } else {
      *(float4*)&out[((size_t)(batch0 + bl) * T_ + tout) * (2 * H_) +
                     dir * H_ + ublk * 16 + uq] = o4;
    }

    const unsigned short* tp = hc; hc = hn; hn = (unsigned short*)tp;
  };

  for (int s = 0; s < T_; s += 2) {
    body(s,     wfA, wfB);     // ends with wfB = N-tile 0
    body(s + 1, wfB, wfA);     // ends with wfA = N-tile 0
  }
}

// ---------------- launch ----------------
extern "C" void kernel_launch(void* const* d_in, const int* in_sizes, int n_in,
                              void* d_out, int out_size, void* d_ws, size_t ws_size,
                              hipStream_t stream) {
  const float* x    = (const float*)d_in[0];
  const float* Wx_f = (const float*)d_in[1];
  const float* bx_f = (const float*)d_in[2];
  const float* Wh_f = (const float*)d_in[3];
  const float* bh_f = (const float*)d_in[4];
  const float* Wx_b = (const float*)d_in[5];
  const float* bx_b = (const float*)d_in[6];
  const float* Wh_b = (const float*)d_in[7];
  const float* bh_b = (const float*)d_in[8];
  float* out = (float*)d_out;

  if (ws_size < WS_NEED) {
    k_sentinel<<<(out_size + 255) / 256, 256, 0, stream>>>(out, out_size);
    return;
  }

  char* ws = (char*)d_ws;
  unsigned short* xp    = (unsigned short*)(ws + OFF_XP);
  unsigned short* xb    = (unsigned short*)(ws + OFF_XB);
  unsigned short* W2x   = (unsigned short*)(ws + OFF_W2X);
  unsigned short* W2h   = (unsigned short*)(ws + OFF_W2H);
  float*          bias2 = (float*)(ws + OFF_BIAS);
  unsigned short* hbuf  = (unsigned short*)(ws + OFF_HB);
  unsigned*       bar   = (unsigned*)(ws + OFF_BAR);

  k_cvt_weights<<<(2 * NROW * KD) / 256, 256, 0, stream>>>(
      Wx_f, Wh_f, Wx_b, Wh_b, bx_f, bh_f, bx_b, bh_b, W2x, W2h, bias2);
  k_cvt_x<<<(B_ * T_ * I_) / 256, 256, 0, stream>>>(x, xb);
  k_zero_h<<<(2 * 2 * B_ * H_) / 256, 256, 0, stream>>>(hbuf, bar);
  k_gemm_xp<<<2 * 20 * 256, 256, 0, stream>>>(W2x, xb, bias2, xp);
  k_recurrent<<<128, 128, 0, stream>>>(W2h, xp, hbuf, out, bar);
}